// Round 2
// baseline (725.911 us; speedup 1.0000x reference)
//
#include <hip/hip_runtime.h>
#include <math.h>

#define SCALE 0.17677669529663687f  // 1/sqrt(32)

// ---------- shared 4x4 FMA micro-kernel ----------
__device__ __forceinline__ void fma4x4(const float4 a, const float4 b, float acc[4][4]) {
    acc[0][0] += a.x * b.x; acc[0][1] += a.x * b.y; acc[0][2] += a.x * b.z; acc[0][3] += a.x * b.w;
    acc[1][0] += a.y * b.x; acc[1][1] += a.y * b.y; acc[1][2] += a.y * b.z; acc[1][3] += a.y * b.w;
    acc[2][0] += a.z * b.x; acc[2][1] += a.z * b.y; acc[2][2] += a.z * b.z; acc[2][3] += a.z * b.w;
    acc[3][0] += a.w * b.x; acc[3][1] += a.w * b.y; acc[3][2] += a.w * b.z; acc[3][3] += a.w * b.w;
}

// ---------- Kernel 1: qkv = x @ qkv_w + qkv_b, scatter to q/k/v (BW,H,N,D), q pre-scaled ----------
// M = 512*98 = 50176 (divisible by 64), K = 256, Ncols = 768
__global__ __launch_bounds__(256) void qkv_gemm_kernel(
    const float* __restrict__ x, const float* __restrict__ w,
    const float* __restrict__ bias,
    float* __restrict__ q, float* __restrict__ k, float* __restrict__ v)
{
    __shared__ float As[16][64];   // transposed A tile: As[k][m]
    __shared__ float Bs[16][64];
    const int tid = threadIdx.x;
    const int tx = tid & 15, ty = tid >> 4;
    const int bm = blockIdx.y * 64;
    const int bn = blockIdx.x * 64;

    float acc[4][4] = {};
    const int ar = tid >> 2;            // 0..63
    const int ac = (tid & 3) << 2;      // 0,4,8,12
    const int br = tid >> 4;            // 0..15
    const int bc = (tid & 15) << 2;     // 0..60

    for (int k0 = 0; k0 < 256; k0 += 16) {
        const float4 av = *(const float4*)(x + (size_t)(bm + ar) * 256 + k0 + ac);
        As[ac + 0][ar] = av.x;
        As[ac + 1][ar] = av.y;
        As[ac + 2][ar] = av.z;
        As[ac + 3][ar] = av.w;
        *(float4*)(&Bs[br][bc]) = *(const float4*)(w + (size_t)(k0 + br) * 768 + bn + bc);
        __syncthreads();
        #pragma unroll
        for (int kk = 0; kk < 16; ++kk) {
            const float4 a = *(const float4*)(&As[kk][ty << 2]);
            const float4 b = *(const float4*)(&Bs[kk][tx << 2]);
            fma4x4(a, b, acc);
        }
        __syncthreads();
    }

    #pragma unroll
    for (int i = 0; i < 4; ++i) {
        const int m = bm + (ty << 2) + i;
        const int bi = m / 98;
        const int n = m - bi * 98;
        #pragma unroll
        for (int j = 0; j < 4; ++j) {
            const int col = bn + (tx << 2) + j;
            const float val = acc[i][j] + bias[col];
            const int s = col >> 8;         // 0=q 1=k 2=v
            const int h = (col >> 5) & 7;
            const int d = col & 31;
            const size_t o = ((((size_t)bi * 8 + h) * 98) + n) * 32 + d;
            if (s == 0)      q[o] = val * SCALE;
            else if (s == 1) k[o] = val;
            else             v[o] = val;
        }
    }
}

// ---------- Kernel 2: per-(b,h) windowed attention ----------
// S = q@k^T + bias[rpi] + mask[b%64]; softmax; O = P@V -> att (BW, N, C)
__global__ __launch_bounds__(256) void attn_kernel(
    const float* __restrict__ q, const float* __restrict__ k,
    const float* __restrict__ v, const float* __restrict__ bias_table,
    const int* __restrict__ rpi, const float* __restrict__ mask,
    float* __restrict__ att)
{
    __shared__ float qs[98][32];
    __shared__ float vs[98][32];
    __shared__ float ksT[32][100];   // K transposed, padded row (conflict-free float2)
    __shared__ float sc[98][100];    // scores

    const int bh = blockIdx.x;
    const int b = bh >> 3, h = bh & 7;
    const int tid = threadIdx.x;
    const float* qp = q + (size_t)bh * (98 * 32);
    const float* kp = k + (size_t)bh * (98 * 32);
    const float* vp = v + (size_t)bh * (98 * 32);

    for (int idx = tid; idx < 98 * 32; idx += 256) {
        const int n = idx >> 5, d = idx & 31;
        qs[n][d] = qp[idx];
        vs[n][d] = vp[idx];
        ksT[d][n] = kp[idx];
    }
    __syncthreads();

    // ---- S = q@k^T (+bias+mask), 2x2 micro-tile per thread ----
    const float* mp = mask + (size_t)(b & 63) * (98 * 98);
    for (int e = tid; e < 49 * 49; e += 256) {
        const int i0 = (e / 49) << 1;
        const int j0 = (e % 49) << 1;
        float s00 = 0.f, s01 = 0.f, s10 = 0.f, s11 = 0.f;
        #pragma unroll
        for (int d = 0; d < 32; ++d) {
            const float a0 = qs[i0][d];
            const float a1 = qs[i0 + 1][d];
            const float2 bk = *(const float2*)(&ksT[d][j0]);
            s00 += a0 * bk.x; s01 += a0 * bk.y;
            s10 += a1 * bk.x; s11 += a1 * bk.y;
        }
        const int p00 = i0 * 98 + j0;
        const int p10 = p00 + 98;
        s00 += bias_table[rpi[p00] * 8 + h] + mp[p00];
        s01 += bias_table[rpi[p00 + 1] * 8 + h] + mp[p00 + 1];
        s10 += bias_table[rpi[p10] * 8 + h] + mp[p10];
        s11 += bias_table[rpi[p10 + 1] * 8 + h] + mp[p10 + 1];
        sc[i0][j0] = s00;     sc[i0][j0 + 1] = s01;
        sc[i0 + 1][j0] = s10; sc[i0 + 1][j0 + 1] = s11;
    }
    __syncthreads();

    // ---- softmax per row: 4 waves, 64-lane shuffle reduce ----
    const int wave = tid >> 6, lane = tid & 63;
    for (int i = wave; i < 98; i += 4) {
        const float x0 = sc[i][lane];
        const float x1 = (lane < 34) ? sc[i][lane + 64] : -INFINITY;
        float mx = fmaxf(x0, x1);
        #pragma unroll
        for (int off = 32; off; off >>= 1) mx = fmaxf(mx, __shfl_xor(mx, off));
        const float e0 = __expf(x0 - mx);
        const float e1 = (lane < 34) ? __expf(x1 - mx) : 0.f;
        float sum = e0 + e1;
        #pragma unroll
        for (int off = 32; off; off >>= 1) sum += __shfl_xor(sum, off);
        const float inv = 1.0f / sum;
        sc[i][lane] = e0 * inv;
        if (lane < 34) sc[i][lane + 64] = e1 * inv;
    }
    __syncthreads();

    // ---- O = P @ V, 2x2 micro-tile; write att[b, i, h*32+d] ----
    float* op = att + ((size_t)b * 98) * 256 + h * 32;
    for (int e = tid; e < 49 * 16; e += 256) {
        const int i0 = (e / 16) << 1;
        const int d0 = (e & 15) << 1;
        float o00 = 0.f, o01 = 0.f, o10 = 0.f, o11 = 0.f;
        for (int j = 0; j < 98; ++j) {
            const float a0 = sc[i0][j];
            const float a1 = sc[i0 + 1][j];
            const float2 bv = *(const float2*)(&vs[j][d0]);
            o00 += a0 * bv.x; o01 += a0 * bv.y;
            o10 += a1 * bv.x; o11 += a1 * bv.y;
        }
        op[(size_t)i0 * 256 + d0]           = o00;
        op[(size_t)i0 * 256 + d0 + 1]       = o01;
        op[(size_t)(i0 + 1) * 256 + d0]     = o10;
        op[(size_t)(i0 + 1) * 256 + d0 + 1] = o11;
    }
}

// ---------- Kernel 3: out = att @ proj_w + proj_b ----------
// M = 50176, K = 256, Ncols = 256
__global__ __launch_bounds__(256) void proj_gemm_kernel(
    const float* __restrict__ A, const float* __restrict__ w,
    const float* __restrict__ pb, float* __restrict__ out)
{
    __shared__ float As[16][64];
    __shared__ float Bs[16][64];
    const int tid = threadIdx.x;
    const int tx = tid & 15, ty = tid >> 4;
    const int bm = blockIdx.y * 64;
    const int bn = blockIdx.x * 64;

    float acc[4][4] = {};
    const int ar = tid >> 2;
    const int ac = (tid & 3) << 2;
    const int br = tid >> 4;
    const int bc = (tid & 15) << 2;

    for (int k0 = 0; k0 < 256; k0 += 16) {
        const float4 av = *(const float4*)(A + (size_t)(bm + ar) * 256 + k0 + ac);
        As[ac + 0][ar] = av.x;
        As[ac + 1][ar] = av.y;
        As[ac + 2][ar] = av.z;
        As[ac + 3][ar] = av.w;
        *(float4*)(&Bs[br][bc]) = *(const float4*)(w + (size_t)(k0 + br) * 256 + bn + bc);
        __syncthreads();
        #pragma unroll
        for (int kk = 0; kk < 16; ++kk) {
            const float4 a = *(const float4*)(&As[kk][ty << 2]);
            const float4 b = *(const float4*)(&Bs[kk][tx << 2]);
            fma4x4(a, b, acc);
        }
        __syncthreads();
    }

    #pragma unroll
    for (int i = 0; i < 4; ++i) {
        const int m = bm + (ty << 2) + i;
        const int col = bn + (tx << 2);
        float4 r;
        r.x = acc[i][0] + pb[col + 0];
        r.y = acc[i][1] + pb[col + 1];
        r.z = acc[i][2] + pb[col + 2];
        r.w = acc[i][3] + pb[col + 3];
        *(float4*)(out + (size_t)m * 256 + col) = r;
    }
}

extern "C" void kernel_launch(void* const* d_in, const int* in_sizes, int n_in,
                              void* d_out, int out_size, void* d_ws, size_t ws_size,
                              hipStream_t stream) {
    const float* x          = (const float*)d_in[0];
    const float* qkv_w      = (const float*)d_in[1];
    const float* qkv_b      = (const float*)d_in[2];
    const float* bias_table = (const float*)d_in[3];
    const float* proj_w     = (const float*)d_in[4];
    const float* proj_b     = (const float*)d_in[5];
    const float* mask       = (const float*)d_in[6];
    const int*   rpi        = (const int*)d_in[7];
    float* out = (float*)d_out;

    // workspace layout (floats): q | k | v | att  (each 512*8*98*32 == 512*98*256 == 12,845,056)
    const size_t SEG = (size_t)512 * 8 * 98 * 32;
    float* q   = (float*)d_ws;
    float* k   = q + SEG;
    float* v   = k + SEG;
    float* att = v + SEG;

    dim3 g1(12, 784);   // 768/64 cols, 50176/64 rows
    qkv_gemm_kernel<<<g1, 256, 0, stream>>>(x, qkv_w, qkv_b, q, k, v);

    attn_kernel<<<4096, 256, 0, stream>>>(q, k, v, bias_table, rpi, mask, att);

    dim3 g3(4, 784);    // 256/64 cols, 50176/64 rows
    proj_gemm_kernel<<<g3, 256, 0, stream>>>(att, proj_w, proj_b, out);
}

// Round 3
// 265.722 us; speedup vs baseline: 2.7318x; 2.7318x over previous
//
#include <hip/hip_runtime.h>
#include <math.h>

typedef short bf8v __attribute__((ext_vector_type(8)));   // 8 bf16 (4 VGPR) MFMA frag
typedef float f32x4 __attribute__((ext_vector_type(4)));  // MFMA acc

#define SCALE 0.17677669529663687f  // 1/sqrt(32)

__device__ __forceinline__ unsigned short f2bf(float f) {
    union { float f; unsigned int u; } c; c.f = f;
    unsigned int r = (c.u + 0x7FFFu + ((c.u >> 16) & 1u)) >> 16;  // RNE
    return (unsigned short)r;
}

// LDS index helpers (element index into ushort arrays).
// [rows][32] bf16 tile, 16B slots; slot XOR (row>>1)&3 -> frag reads are 2-way (free)
__device__ __forceinline__ int sw32(int row, int k8) {
    return row * 32 + ((k8 ^ ((row >> 1) & 3)) << 3);
}
// [rows][128] bf16 tile, 16 slots; slot XOR row&15 -> frag reads perfect 2-way
__device__ __forceinline__ int sw128(int row, int c8) {
    return row * 128 + (((c8 ^ row) & 15) << 3);
}

// ---------- pre-kernel: x fp32 -> bf16 ----------
__global__ __launch_bounds__(256) void cvt_x_kernel(const float* __restrict__ in,
                                                    unsigned short* __restrict__ out, int n8) {
    int i = blockIdx.x * 256 + threadIdx.x;
    if (i >= n8) return;
    const float4* p = (const float4*)(in + (size_t)i * 8);
    float4 a = p[0], b = p[1];
    union { int4 v; unsigned short u[8]; } o;
    o.u[0]=f2bf(a.x); o.u[1]=f2bf(a.y); o.u[2]=f2bf(a.z); o.u[3]=f2bf(a.w);
    o.u[4]=f2bf(b.x); o.u[5]=f2bf(b.y); o.u[6]=f2bf(b.z); o.u[7]=f2bf(b.w);
    *(int4*)(out + (size_t)i * 8) = o.v;
}

// ---------- pre-kernel: w [256][C] fp32 -> wt [C][256] bf16 (transpose+convert) ----------
__global__ __launch_bounds__(256) void tcvt_w_kernel(const float* __restrict__ in,
                                                     unsigned short* __restrict__ out, int C) {
    int idx = blockIdx.x * 256 + threadIdx.x;  // output-linear over [C][256]
    int c = idx >> 8, r = idx & 255;
    if (c < C) out[idx] = f2bf(in[r * C + c]);
}

// ---------- pre-kernel: bm[w][h][i*98+j] = bias_table[rpi]+mask ----------
__global__ __launch_bounds__(256) void bm_kernel(const float* __restrict__ bias_table,
                                                 const int* __restrict__ rpi,
                                                 const float* __restrict__ mask,
                                                 float* __restrict__ bm) {
    int bx = blockIdx.x;               // bx = w*8 + h
    int w = bx >> 3, h = bx & 7;
    const float* mp = mask + (size_t)w * 9604;
    float* op = bm + (size_t)bx * 9604;
    for (int e = threadIdx.x; e < 9604; e += 256)
        op[e] = bias_table[rpi[e] * 8 + h] + mp[e];
}

// ---------- Kernel 1: qkv GEMM (bf16 MFMA), scatter to q/k/v bf16 [b][h][n][d], q pre-scaled ----------
// M=50176, K=256, N=768. 128x128 tile, BK=32, 4 waves, 64x64 per wave.
__global__ __launch_bounds__(256) void qkv_gemm_kernel(
    const unsigned short* __restrict__ A, const unsigned short* __restrict__ B,
    const float* __restrict__ bias,
    unsigned short* __restrict__ q, unsigned short* __restrict__ k, unsigned short* __restrict__ v)
{
    __shared__ unsigned short As[128 * 32];
    __shared__ unsigned short Bs[128 * 32];
    const int tid = threadIdx.x;
    const int lane = tid & 63, wid = tid >> 6;
    const int l16 = lane & 15, lg = lane >> 4;
    const int wr = wid >> 1, wc = wid & 1;
    const int bm0 = blockIdx.y * 128, bn0 = blockIdx.x * 128;

    f32x4 acc[4][4] = {};
    const int crow = tid >> 2, ck8 = tid & 3;  // staging chunk (16B): 512 chunks, 2/thread

    for (int k0 = 0; k0 < 256; k0 += 32) {
        __syncthreads();
        *(int4*)&As[sw32(crow,      ck8)] = *(const int4*)(A + (size_t)(bm0 + crow     ) * 256 + k0 + ck8 * 8);
        *(int4*)&As[sw32(crow + 64, ck8)] = *(const int4*)(A + (size_t)(bm0 + crow + 64) * 256 + k0 + ck8 * 8);
        *(int4*)&Bs[sw32(crow,      ck8)] = *(const int4*)(B + (size_t)(bn0 + crow     ) * 256 + k0 + ck8 * 8);
        *(int4*)&Bs[sw32(crow + 64, ck8)] = *(const int4*)(B + (size_t)(bn0 + crow + 64) * 256 + k0 + ck8 * 8);
        __syncthreads();
        bf8v af[4], bfr[4];
        #pragma unroll
        for (int mt = 0; mt < 4; ++mt) af[mt]  = *(const bf8v*)&As[sw32(wr*64 + mt*16 + l16, lg)];
        #pragma unroll
        for (int nt = 0; nt < 4; ++nt) bfr[nt] = *(const bf8v*)&Bs[sw32(wc*64 + nt*16 + l16, lg)];
        #pragma unroll
        for (int mt = 0; mt < 4; ++mt)
            #pragma unroll
            for (int nt = 0; nt < 4; ++nt)
                acc[mt][nt] = __builtin_amdgcn_mfma_f32_16x16x32_bf16(af[mt], bfr[nt], acc[mt][nt], 0, 0, 0);
    }

    #pragma unroll
    for (int mt = 0; mt < 4; ++mt) {
        #pragma unroll
        for (int r = 0; r < 4; ++r) {
            const int row = bm0 + wr*64 + mt*16 + lg*4 + r;  // D: row = lg*4 + reg
            const int bi = row / 98, n = row - bi * 98;
            const size_t rb = ((size_t)bi * 8 * 98 + n) * 32;
            #pragma unroll
            for (int nt = 0; nt < 4; ++nt) {
                const int col = bn0 + wc*64 + nt*16 + l16;   // D: col = lane&15
                const float val = acc[mt][nt][r] + bias[col];
                const int h = (col >> 5) & 7, d = col & 31;
                const size_t o = rb + (size_t)h * (98 * 32) + d;
                if (col < 256)      q[o] = f2bf(val * SCALE);
                else if (col < 512) k[o] = f2bf(val);
                else                v[o] = f2bf(val);
            }
        }
    }
}

// ---------- Kernel 2: per-(b,h) attention, MFMA QK^T + in-reg softmax + MFMA PV ----------
// 7 waves, one 16-row tile each. N=98 padded to 112 (rows/cols), PV K padded to 128.
__global__ __launch_bounds__(448) void attn_kernel(
    const unsigned short* __restrict__ q, const unsigned short* __restrict__ k,
    const unsigned short* __restrict__ v, const float* __restrict__ bm,
    unsigned short* __restrict__ att)
{
    __shared__ unsigned short Qs[112 * 32];
    __shared__ unsigned short Ks[112 * 32];
    __shared__ unsigned short Vt[32 * 128];   // V transposed: Vt[d][kp]
    __shared__ unsigned short Ps[112 * 128];  // softmax'd P in bf16

    const int bh = blockIdx.x;
    const int b = bh >> 3, h = bh & 7;
    const int tid = threadIdx.x;
    const int wid = tid >> 6, lane = tid & 63;
    const int l16 = lane & 15, lg = lane >> 4;
    const unsigned short* qp = q + (size_t)bh * 3136;
    const unsigned short* kp = k + (size_t)bh * 3136;
    const unsigned short* vp = v + (size_t)bh * 3136;

    // ---- stage Q,K (swizzled), V transposed; zero pads ----
    if (tid < 392) {
        const int row = tid >> 2, k8 = tid & 3;
        *(int4*)&Qs[sw32(row, k8)] = *(const int4*)(qp + row * 32 + k8 * 8);
        *(int4*)&Ks[sw32(row, k8)] = *(const int4*)(kp + row * 32 + k8 * 8);
        union { int4 v; unsigned short u[8]; } t;
        t.v = *(const int4*)(vp + row * 32 + k8 * 8);   // V[row][8d]
        #pragma unroll
        for (int j = 0; j < 8; ++j) {
            const int d = k8 * 8 + j;
            Vt[sw128(d, row >> 3) + (row & 7)] = t.u[j];
        }
    } else {
        const int t2 = tid - 392;                        // 56 threads: zero Q/K pad rows 98..111
        const int row = 98 + (t2 >> 2), k8 = t2 & 3;
        const int4 z = {0, 0, 0, 0};
        *(int4*)&Qs[sw32(row, k8)] = z;
        *(int4*)&Ks[sw32(row, k8)] = z;
    }
    for (int e = tid; e < 32 * 30; e += 448) {           // zero Vt cols 98..127
        const int d = e / 30, n = 98 + e - (e / 30) * 30;
        Vt[sw128(d, n >> 3) + (n & 7)] = 0;
    }
    __syncthreads();

    // ---- S = Q@K^T for row-tile rt = wid ----
    const int rt = wid;
    const bf8v qf = *(const bf8v*)&Qs[sw32(rt * 16 + l16, lg)];
    f32x4 sa[7];
    const f32x4 zero = {0.f, 0.f, 0.f, 0.f};
    #pragma unroll
    for (int ct = 0; ct < 7; ++ct) {
        const bf8v kf = *(const bf8v*)&Ks[sw32(ct * 16 + l16, lg)];
        sa[ct] = __builtin_amdgcn_mfma_f32_16x16x32_bf16(qf, kf, zero, 0, 0, 0);
    }

    // ---- + bias+mask (precomputed bm), mask cols>=98 to -inf ----
    const float* bmp = bm + (size_t)((b & 63) * 8 + h) * 9604;
    #pragma unroll
    for (int ct = 0; ct < 7; ++ct) {
        const int col = ct * 16 + l16;
        const int colc = col < 98 ? col : 97;
        #pragma unroll
        for (int r = 0; r < 4; ++r) {
            const int row = rt * 16 + lg * 4 + r;
            const int rowc = row < 98 ? row : 97;
            const float add = bmp[rowc * 98 + colc];
            sa[ct][r] = (col < 98) ? (sa[ct][r] + add) : -INFINITY;
        }
    }

    // ---- softmax per row (rows live in 16-lane groups), write P bf16 to LDS ----
    #pragma unroll
    for (int r = 0; r < 4; ++r) {
        float mx = sa[0][r];
        #pragma unroll
        for (int ct = 1; ct < 7; ++ct) mx = fmaxf(mx, sa[ct][r]);
        #pragma unroll
        for (int off = 1; off < 16; off <<= 1) mx = fmaxf(mx, __shfl_xor(mx, off));
        float sum = 0.f;
        #pragma unroll
        for (int ct = 0; ct < 7; ++ct) { const float e = __expf(sa[ct][r] - mx); sa[ct][r] = e; sum += e; }
        #pragma unroll
        for (int off = 1; off < 16; off <<= 1) sum += __shfl_xor(sum, off);
        const float inv = 1.0f / sum;
        const int row = rt * 16 + lg * 4 + r;
        #pragma unroll
        for (int ct = 0; ct < 7; ++ct) {
            const int col = ct * 16 + l16;
            Ps[sw128(row, col >> 3) + (col & 7)] = f2bf(sa[ct][r] * inv);
        }
    }
    // zero P pad cols 112..127 for this wave's rows (PV K-dim padding)
    #pragma unroll
    for (int e0 = 0; e0 < 4; ++e0) {
        const int e = e0 * 64 + lane;
        const int row = rt * 16 + (e >> 4), col = 112 + (e & 15);
        Ps[sw128(row, col >> 3) + (col & 7)] = 0;
    }
    // P is wave-local (each wave reads only its own rows) -> no barrier needed.

    // ---- O = P @ V ----
    f32x4 oacc[2] = {};
    #pragma unroll
    for (int ks = 0; ks < 4; ++ks) {
        const bf8v pf = *(const bf8v*)&Ps[sw128(rt * 16 + l16, ks * 4 + lg)];
        #pragma unroll
        for (int dt = 0; dt < 2; ++dt) {
            const bf8v vf = *(const bf8v*)&Vt[sw128(dt * 16 + l16, ks * 4 + lg)];
            oacc[dt] = __builtin_amdgcn_mfma_f32_16x16x32_bf16(pf, vf, oacc[dt], 0, 0, 0);
        }
    }

    // ---- store att[b][row][h*32 + d] bf16 ----
    #pragma unroll
    for (int r = 0; r < 4; ++r) {
        const int row = rt * 16 + lg * 4 + r;
        if (row < 98) {
            #pragma unroll
            for (int dt = 0; dt < 2; ++dt)
                att[((size_t)b * 98 + row) * 256 + h * 32 + dt * 16 + l16] = f2bf(oacc[dt][r]);
        }
    }
}

// ---------- Kernel 3: out = att @ proj_w + proj_b (bf16 MFMA, fp32 out) ----------
// M=50176, K=256, N=256.
__global__ __launch_bounds__(256) void proj_gemm_kernel(
    const unsigned short* __restrict__ A, const unsigned short* __restrict__ B,
    const float* __restrict__ pb, float* __restrict__ out)
{
    __shared__ unsigned short As[128 * 32];
    __shared__ unsigned short Bs[128 * 32];
    const int tid = threadIdx.x;
    const int lane = tid & 63, wid = tid >> 6;
    const int l16 = lane & 15, lg = lane >> 4;
    const int wr = wid >> 1, wc = wid & 1;
    const int bm0 = blockIdx.y * 128, bn0 = blockIdx.x * 128;

    f32x4 acc[4][4] = {};
    const int crow = tid >> 2, ck8 = tid & 3;

    for (int k0 = 0; k0 < 256; k0 += 32) {
        __syncthreads();
        *(int4*)&As[sw32(crow,      ck8)] = *(const int4*)(A + (size_t)(bm0 + crow     ) * 256 + k0 + ck8 * 8);
        *(int4*)&As[sw32(crow + 64, ck8)] = *(const int4*)(A + (size_t)(bm0 + crow + 64) * 256 + k0 + ck8 * 8);
        *(int4*)&Bs[sw32(crow,      ck8)] = *(const int4*)(B + (size_t)(bn0 + crow     ) * 256 + k0 + ck8 * 8);
        *(int4*)&Bs[sw32(crow + 64, ck8)] = *(const int4*)(B + (size_t)(bn0 + crow + 64) * 256 + k0 + ck8 * 8);
        __syncthreads();
        bf8v af[4], bfr[4];
        #pragma unroll
        for (int mt = 0; mt < 4; ++mt) af[mt]  = *(const bf8v*)&As[sw32(wr*64 + mt*16 + l16, lg)];
        #pragma unroll
        for (int nt = 0; nt < 4; ++nt) bfr[nt] = *(const bf8v*)&Bs[sw32(wc*64 + nt*16 + l16, lg)];
        #pragma unroll
        for (int mt = 0; mt < 4; ++mt)
            #pragma unroll
            for (int nt = 0; nt < 4; ++nt)
                acc[mt][nt] = __builtin_amdgcn_mfma_f32_16x16x32_bf16(af[mt], bfr[nt], acc[mt][nt], 0, 0, 0);
    }

    #pragma unroll
    for (int mt = 0; mt < 4; ++mt)
        #pragma unroll
        for (int r = 0; r < 4; ++r) {
            const int row = bm0 + wr*64 + mt*16 + lg*4 + r;
            #pragma unroll
            for (int nt = 0; nt < 4; ++nt) {
                const int col = bn0 + wc*64 + nt*16 + l16;
                out[(size_t)row * 256 + col] = acc[mt][nt][r] + pb[col];
            }
        }
}

extern "C" void kernel_launch(void* const* d_in, const int* in_sizes, int n_in,
                              void* d_out, int out_size, void* d_ws, size_t ws_size,
                              hipStream_t stream) {
    const float* x          = (const float*)d_in[0];
    const float* qkv_w      = (const float*)d_in[1];
    const float* qkv_b      = (const float*)d_in[2];
    const float* bias_table = (const float*)d_in[3];
    const float* proj_w     = (const float*)d_in[4];
    const float* proj_b     = (const float*)d_in[5];
    const float* mask       = (const float*)d_in[6];
    const int*   rpi        = (const int*)d_in[7];
    float* out = (float*)d_out;

    // ws layout (ushorts unless noted): xb | wtq | wtp | q | k | v | att | bm(f32)
    const size_t SEG = (size_t)50176 * 256;  // 12,845,056
    unsigned short* xb  = (unsigned short*)d_ws;
    unsigned short* wtq = xb + SEG;            // 768*256
    unsigned short* wtp = wtq + 768 * 256;     // 256*256
    unsigned short* qb  = wtp + 256 * 256;
    unsigned short* kb  = qb + SEG;
    unsigned short* vb  = kb + SEG;
    unsigned short* attb = vb + SEG;
    float* bm = (float*)(attb + SEG);          // 512*9604 floats

    cvt_x_kernel<<<6272, 256, 0, stream>>>(x, xb, (int)(SEG / 8));
    tcvt_w_kernel<<<768, 256, 0, stream>>>(qkv_w, wtq, 768);
    tcvt_w_kernel<<<256, 256, 0, stream>>>(proj_w, wtp, 256);
    bm_kernel<<<512, 256, 0, stream>>>(bias_table, rpi, mask, bm);

    qkv_gemm_kernel<<<dim3(6, 392), 256, 0, stream>>>(xb, wtq, qkv_b, qb, kb, vb);
    attn_kernel<<<4096, 448, 0, stream>>>(qb, kb, vb, bm, attb);
    proj_gemm_kernel<<<dim3(2, 392), 256, 0, stream>>>(attb, wtp, proj_b, out);
}

// Round 4
// 262.778 us; speedup vs baseline: 2.7625x; 1.0112x over previous
//
#include <hip/hip_runtime.h>
#include <math.h>

typedef short bf8v __attribute__((ext_vector_type(8)));   // 8 bf16 (4 VGPR) MFMA frag
typedef float f32x4 __attribute__((ext_vector_type(4)));  // MFMA acc

#define SCALE 0.17677669529663687f  // 1/sqrt(32)

__device__ __forceinline__ unsigned short f2bf(float f) {
    union { float f; unsigned int u; } c; c.f = f;
    unsigned int r = (c.u + 0x7FFFu + ((c.u >> 16) & 1u)) >> 16;  // RNE
    return (unsigned short)r;
}

// LDS index helpers (element index into ushort arrays).
// [rows][32] bf16 tile, 16B slots; slot XOR (row>>1)&3 -> frag reads are 2-way (free)
__device__ __forceinline__ int sw32(int row, int k8) {
    return row * 32 + ((k8 ^ ((row >> 1) & 3)) << 3);
}
// [rows][128] bf16 tile, 16 slots; slot XOR row&15 -> frag reads perfect 2-way
__device__ __forceinline__ int sw128(int row, int c8) {
    return row * 128 + (((c8 ^ row) & 15) << 3);
}
// bounce buffer [128][128] bf16: XOR chunk bits 1..2 with row-quad -> conflict-free
// on 2B writes (lg groups hit disjoint bank octets) and b128 readback
__device__ __forceinline__ int bidx(int row, int col) {
    return row * 128 + ((((col >> 3) ^ (((row >> 2) & 3) << 1)) & 15) << 3) + (col & 7);
}

// ---------- pre-kernel: x fp32 -> bf16 ----------
__global__ __launch_bounds__(256) void cvt_x_kernel(const float* __restrict__ in,
                                                    unsigned short* __restrict__ out, int n8) {
    int i = blockIdx.x * 256 + threadIdx.x;
    if (i >= n8) return;
    const float4* p = (const float4*)(in + (size_t)i * 8);
    float4 a = p[0], b = p[1];
    union { int4 v; unsigned short u[8]; } o;
    o.u[0]=f2bf(a.x); o.u[1]=f2bf(a.y); o.u[2]=f2bf(a.z); o.u[3]=f2bf(a.w);
    o.u[4]=f2bf(b.x); o.u[5]=f2bf(b.y); o.u[6]=f2bf(b.z); o.u[7]=f2bf(b.w);
    *(int4*)(out + (size_t)i * 8) = o.v;
}

// ---------- pre-kernel: w [256][C] fp32 -> wt [C][256] bf16 (transpose+convert) ----------
__global__ __launch_bounds__(256) void tcvt_w_kernel(const float* __restrict__ in,
                                                     unsigned short* __restrict__ out, int C) {
    int idx = blockIdx.x * 256 + threadIdx.x;  // output-linear over [C][256]
    int c = idx >> 8, r = idx & 255;
    if (c < C) out[idx] = f2bf(in[r * C + c]);
}

// ---------- pre-kernel: bm[w][h][i*98+j] = bias_table[rpi]+mask ----------
__global__ __launch_bounds__(256) void bm_kernel(const float* __restrict__ bias_table,
                                                 const int* __restrict__ rpi,
                                                 const float* __restrict__ mask,
                                                 float* __restrict__ bm) {
    int bx = blockIdx.x;               // bx = w*8 + h
    int w = bx >> 3, h = bx & 7;
    const float* mp = mask + (size_t)w * 9604;
    float* op = bm + (size_t)bx * 9604;
    for (int e = threadIdx.x; e < 9604; e += 256)
        op[e] = bias_table[rpi[e] * 8 + h] + mp[e];
}

// ---------- Kernel 1: qkv GEMM (bf16 MFMA) -> packed qkv [M][768] bf16, q cols pre-scaled ----------
// M=50176, K=256, N=768. 128x128 tile, BK=32, 4 waves. 1D grid 2352 with XCD swizzle.
__global__ __launch_bounds__(256) void qkv_gemm_kernel(
    const unsigned short* __restrict__ A, const unsigned short* __restrict__ B,
    const float* __restrict__ bias, unsigned short* __restrict__ qkv)
{
    __shared__ unsigned short As[128 * 32];
    __shared__ unsigned short Bs[128 * 32];
    __shared__ unsigned short Cb[128 * 128];
    const int tid = threadIdx.x;
    const int lane = tid & 63, wid = tid >> 6;
    const int l16 = lane & 15, lg = lane >> 4;
    const int wr = wid >> 1, wc = wid & 1;
    // XCD-bijective swizzle: 2352 = 8*294; each XCD gets 294 consecutive (col fastest)
    const int nb = (blockIdx.x & 7) * 294 + (blockIdx.x >> 3);
    const int bm0 = (nb / 6) * 128, bn0 = (nb % 6) * 128;

    f32x4 acc[4][4] = {};
    const int crow = tid >> 2, ck8 = tid & 3;  // staging chunk (16B)

    for (int k0 = 0; k0 < 256; k0 += 32) {
        __syncthreads();
        *(int4*)&As[sw32(crow,      ck8)] = *(const int4*)(A + (size_t)(bm0 + crow     ) * 256 + k0 + ck8 * 8);
        *(int4*)&As[sw32(crow + 64, ck8)] = *(const int4*)(A + (size_t)(bm0 + crow + 64) * 256 + k0 + ck8 * 8);
        *(int4*)&Bs[sw32(crow,      ck8)] = *(const int4*)(B + (size_t)(bn0 + crow     ) * 256 + k0 + ck8 * 8);
        *(int4*)&Bs[sw32(crow + 64, ck8)] = *(const int4*)(B + (size_t)(bn0 + crow + 64) * 256 + k0 + ck8 * 8);
        __syncthreads();
        bf8v af[4], bfr[4];
        #pragma unroll
        for (int mt = 0; mt < 4; ++mt) af[mt]  = *(const bf8v*)&As[sw32(wr*64 + mt*16 + l16, lg)];
        #pragma unroll
        for (int nt = 0; nt < 4; ++nt) bfr[nt] = *(const bf8v*)&Bs[sw32(wc*64 + nt*16 + l16, lg)];
        #pragma unroll
        for (int mt = 0; mt < 4; ++mt)
            #pragma unroll
            for (int nt = 0; nt < 4; ++nt)
                acc[mt][nt] = __builtin_amdgcn_mfma_f32_16x16x32_bf16(af[mt], bfr[nt], acc[mt][nt], 0, 0, 0);
    }

    // epilogue: bias+scale -> bf16 -> swizzled LDS bounce -> coalesced int4 stores
    #pragma unroll
    for (int nt = 0; nt < 4; ++nt) {
        const int colg = bn0 + wc * 64 + nt * 16 + l16;
        const float bv = bias[colg];
        const float sc = (colg < 256) ? SCALE : 1.0f;
        #pragma unroll
        for (int mt = 0; mt < 4; ++mt)
            #pragma unroll
            for (int r = 0; r < 4; ++r) {
                const int rl = wr * 64 + mt * 16 + lg * 4 + r;
                Cb[bidx(rl, wc * 64 + nt * 16 + l16)] = f2bf((acc[mt][nt][r] + bv) * sc);
            }
    }
    __syncthreads();
    #pragma unroll
    for (int c0 = 0; c0 < 8; ++c0) {
        const int c = c0 * 256 + tid;
        const int row = c >> 4, c8 = c & 15;
        const int4 val = *(const int4*)&Cb[row * 128 + (((c8 ^ (((row >> 2) & 3) << 1)) & 15) << 3)];
        *(int4*)(qkv + (size_t)(bm0 + row) * 768 + bn0 + c8 * 8) = val;
    }
}

// ---------- Kernel 2: per-(b,h) attention, MFMA QK^T + in-reg softmax + MFMA PV ----------
// reads packed qkv [b][n][768]; 7 waves, one 16-row tile each.
__global__ __launch_bounds__(448) void attn_kernel(
    const unsigned short* __restrict__ qkv, const float* __restrict__ bm,
    unsigned short* __restrict__ att)
{
    __shared__ unsigned short Qs[112 * 32];
    __shared__ unsigned short Ks[112 * 32];
    __shared__ unsigned short Vt[32 * 128];   // V transposed: Vt[d][kp]
    __shared__ unsigned short Ps[112 * 128];  // softmax'd P in bf16

    // XCD-bijective swizzle: 4096 = 8*512; all 8 h of a b land on the same XCD
    const int nb = (blockIdx.x & 7) * 512 + (blockIdx.x >> 3);
    const int b = nb >> 3, h = nb & 7;
    const int tid = threadIdx.x;
    const int wid = tid >> 6, lane = tid & 63;
    const int l16 = lane & 15, lg = lane >> 4;
    const unsigned short* base = qkv + (size_t)b * 98 * 768 + h * 32;  // q; +256 k; +512 v

    // ---- stage Q,K (swizzled), V transposed; zero pads ----
    if (tid < 392) {
        const int row = tid >> 2, k8 = tid & 3;
        const unsigned short* rp = base + (size_t)row * 768 + k8 * 8;
        *(int4*)&Qs[sw32(row, k8)] = *(const int4*)(rp);
        *(int4*)&Ks[sw32(row, k8)] = *(const int4*)(rp + 256);
        union { int4 v; unsigned short u[8]; } t;
        t.v = *(const int4*)(rp + 512);   // V[row][8d]
        #pragma unroll
        for (int j = 0; j < 8; ++j) {
            const int d = k8 * 8 + j;
            Vt[sw128(d, row >> 3) + (row & 7)] = t.u[j];
        }
    } else {
        const int t2 = tid - 392;                        // 56 threads: zero Q/K pad rows 98..111
        const int row = 98 + (t2 >> 2), k8 = t2 & 3;
        const int4 z = {0, 0, 0, 0};
        *(int4*)&Qs[sw32(row, k8)] = z;
        *(int4*)&Ks[sw32(row, k8)] = z;
    }
    for (int e = tid; e < 32 * 30; e += 448) {           // zero Vt cols 98..127
        const int d = e / 30, n = 98 + e - (e / 30) * 30;
        Vt[sw128(d, n >> 3) + (n & 7)] = 0;
    }
    __syncthreads();

    // ---- S = Q@K^T for row-tile rt = wid ----
    const int rt = wid;
    const bf8v qf = *(const bf8v*)&Qs[sw32(rt * 16 + l16, lg)];
    f32x4 sa[7];
    const f32x4 zero = {0.f, 0.f, 0.f, 0.f};
    #pragma unroll
    for (int ct = 0; ct < 7; ++ct) {
        const bf8v kf = *(const bf8v*)&Ks[sw32(ct * 16 + l16, lg)];
        sa[ct] = __builtin_amdgcn_mfma_f32_16x16x32_bf16(qf, kf, zero, 0, 0, 0);
    }

    // ---- + bias+mask (precomputed bm), mask cols>=98 to -inf ----
    const float* bmp = bm + (size_t)((b & 63) * 8 + h) * 9604;
    #pragma unroll
    for (int ct = 0; ct < 7; ++ct) {
        const int col = ct * 16 + l16;
        const int colc = col < 98 ? col : 97;
        #pragma unroll
        for (int r = 0; r < 4; ++r) {
            const int row = rt * 16 + lg * 4 + r;
            const int rowc = row < 98 ? row : 97;
            const float add = bmp[rowc * 98 + colc];
            sa[ct][r] = (col < 98) ? (sa[ct][r] + add) : -INFINITY;
        }
    }

    // ---- softmax per row (rows live in 16-lane groups), write P bf16 to LDS ----
    #pragma unroll
    for (int r = 0; r < 4; ++r) {
        float mx = sa[0][r];
        #pragma unroll
        for (int ct = 1; ct < 7; ++ct) mx = fmaxf(mx, sa[ct][r]);
        #pragma unroll
        for (int off = 1; off < 16; off <<= 1) mx = fmaxf(mx, __shfl_xor(mx, off));
        float sum = 0.f;
        #pragma unroll
        for (int ct = 0; ct < 7; ++ct) { const float e = __expf(sa[ct][r] - mx); sa[ct][r] = e; sum += e; }
        #pragma unroll
        for (int off = 1; off < 16; off <<= 1) sum += __shfl_xor(sum, off);
        const float inv = 1.0f / sum;
        const int row = rt * 16 + lg * 4 + r;
        #pragma unroll
        for (int ct = 0; ct < 7; ++ct) {
            const int col = ct * 16 + l16;
            Ps[sw128(row, col >> 3) + (col & 7)] = f2bf(sa[ct][r] * inv);
        }
    }
    // zero P pad cols 112..127 for this wave's rows (PV K-dim padding)
    #pragma unroll
    for (int e0 = 0; e0 < 4; ++e0) {
        const int e = e0 * 64 + lane;
        const int row = rt * 16 + (e >> 4), col = 112 + (e & 15);
        Ps[sw128(row, col >> 3) + (col & 7)] = 0;
    }
    // P is wave-local (each wave reads only its own rows) -> no barrier needed.

    // ---- O = P @ V ----
    f32x4 oacc[2] = {};
    #pragma unroll
    for (int ks = 0; ks < 4; ++ks) {
        const bf8v pf = *(const bf8v*)&Ps[sw128(rt * 16 + l16, ks * 4 + lg)];
        #pragma unroll
        for (int dt = 0; dt < 2; ++dt) {
            const bf8v vf = *(const bf8v*)&Vt[sw128(dt * 16 + l16, ks * 4 + lg)];
            oacc[dt] = __builtin_amdgcn_mfma_f32_16x16x32_bf16(pf, vf, oacc[dt], 0, 0, 0);
        }
    }

    // ---- store att[b][row][h*32 + d] bf16 ----
    #pragma unroll
    for (int r = 0; r < 4; ++r) {
        const int row = rt * 16 + lg * 4 + r;
        if (row < 98) {
            #pragma unroll
            for (int dt = 0; dt < 2; ++dt)
                att[((size_t)b * 98 + row) * 256 + h * 32 + dt * 16 + l16] = f2bf(oacc[dt][r]);
        }
    }
}

// ---------- Kernel 3: out = att @ proj_w + proj_b (bf16 MFMA, fp32 out) ----------
// M=50176, K=256, N=256. 1D grid 784 with XCD swizzle.
__global__ __launch_bounds__(256) void proj_gemm_kernel(
    const unsigned short* __restrict__ A, const unsigned short* __restrict__ B,
    const float* __restrict__ pb, float* __restrict__ out)
{
    __shared__ unsigned short As[128 * 32];
    __shared__ unsigned short Bs[128 * 32];
    const int tid = threadIdx.x;
    const int lane = tid & 63, wid = tid >> 6;
    const int l16 = lane & 15, lg = lane >> 4;
    const int wr = wid >> 1, wc = wid & 1;
    // XCD-bijective swizzle: 784 = 8*98
    const int nb = (blockIdx.x & 7) * 98 + (blockIdx.x >> 3);
    const int bm0 = (nb >> 1) * 128, bn0 = (nb & 1) * 128;

    f32x4 acc[4][4] = {};
    const int crow = tid >> 2, ck8 = tid & 3;

    for (int k0 = 0; k0 < 256; k0 += 32) {
        __syncthreads();
        *(int4*)&As[sw32(crow,      ck8)] = *(const int4*)(A + (size_t)(bm0 + crow     ) * 256 + k0 + ck8 * 8);
        *(int4*)&As[sw32(crow + 64, ck8)] = *(const int4*)(A + (size_t)(bm0 + crow + 64) * 256 + k0 + ck8 * 8);
        *(int4*)&Bs[sw32(crow,      ck8)] = *(const int4*)(B + (size_t)(bn0 + crow     ) * 256 + k0 + ck8 * 8);
        *(int4*)&Bs[sw32(crow + 64, ck8)] = *(const int4*)(B + (size_t)(bn0 + crow + 64) * 256 + k0 + ck8 * 8);
        __syncthreads();
        bf8v af[4], bfr[4];
        #pragma unroll
        for (int mt = 0; mt < 4; ++mt) af[mt]  = *(const bf8v*)&As[sw32(wr*64 + mt*16 + l16, lg)];
        #pragma unroll
        for (int nt = 0; nt < 4; ++nt) bfr[nt] = *(const bf8v*)&Bs[sw32(wc*64 + nt*16 + l16, lg)];
        #pragma unroll
        for (int mt = 0; mt < 4; ++mt)
            #pragma unroll
            for (int nt = 0; nt < 4; ++nt)
                acc[mt][nt] = __builtin_amdgcn_mfma_f32_16x16x32_bf16(af[mt], bfr[nt], acc[mt][nt], 0, 0, 0);
    }

    #pragma unroll
    for (int mt = 0; mt < 4; ++mt)
        #pragma unroll
        for (int r = 0; r < 4; ++r) {
            const int row = bm0 + wr*64 + mt*16 + lg*4 + r;
            #pragma unroll
            for (int nt = 0; nt < 4; ++nt) {
                const int col = bn0 + wc*64 + nt*16 + l16;
                out[(size_t)row * 256 + col] = acc[mt][nt][r] + pb[col];
            }
        }
}

extern "C" void kernel_launch(void* const* d_in, const int* in_sizes, int n_in,
                              void* d_out, int out_size, void* d_ws, size_t ws_size,
                              hipStream_t stream) {
    const float* x          = (const float*)d_in[0];
    const float* qkv_w      = (const float*)d_in[1];
    const float* qkv_b      = (const float*)d_in[2];
    const float* bias_table = (const float*)d_in[3];
    const float* proj_w     = (const float*)d_in[4];
    const float* proj_b     = (const float*)d_in[5];
    const float* mask       = (const float*)d_in[6];
    const int*   rpi        = (const int*)d_in[7];
    float* out = (float*)d_out;

    // ws layout (ushorts unless noted): xb | wtq | wtp | qkv | att | bm(f32)
    const size_t SEG = (size_t)50176 * 256;  // 12,845,056
    unsigned short* xb   = (unsigned short*)d_ws;
    unsigned short* wtq  = xb + SEG;            // 768*256
    unsigned short* wtp  = wtq + 768 * 256;     // 256*256
    unsigned short* qkvb = wtp + 256 * 256;     // 3*SEG, packed [M][768]
    unsigned short* attb = qkvb + 3 * SEG;
    float* bm = (float*)(attb + SEG);           // 512*9604 floats

    cvt_x_kernel<<<6272, 256, 0, stream>>>(x, xb, (int)(SEG / 8));
    tcvt_w_kernel<<<768, 256, 0, stream>>>(qkv_w, wtq, 768);
    tcvt_w_kernel<<<256, 256, 0, stream>>>(proj_w, wtp, 256);
    bm_kernel<<<512, 256, 0, stream>>>(bias_table, rpi, mask, bm);

    qkv_gemm_kernel<<<2352, 256, 0, stream>>>(xb, wtq, qkv_b, qkvb);
    attn_kernel<<<4096, 448, 0, stream>>>(qkvb, bm, attb);
    proj_gemm_kernel<<<784, 256, 0, stream>>>(attb, wtp, proj_b, out);
}